// Round 21
// baseline (270.128 us; speedup 1.0000x reference)
//
#include <hip/hip_runtime.h>
#include <hip/hip_bf16.h>

#define MUL 32
#define SCAN_CH 1024

typedef _Float16 f16x8 __attribute__((ext_vector_type(8)));
typedef float f32x4 __attribute__((ext_vector_type(4)));

static __device__ __forceinline__ float silu_f(float z) {
    return z / (1.0f + __expf(-z));
}

// ---------------------------------------------------------------------------
// Kernel A: per-node pre-pass, wave-per-node, barrier-free. (r14-r20 verified)
// ---------------------------------------------------------------------------
__global__ __launch_bounds__(256) void node_pre_kernel(
    const float* __restrict__ x, const float* __restrict__ attr,
    const float* __restrict__ Wsc0, const float* __restrict__ Wsc1,
    const float* __restrict__ Wl10, const float* __restrict__ Wl11,
    float* __restrict__ sc_out, _Float16* __restrict__ y_out, int N)
{
    __shared__ float sX[4][128];
    const int tid = threadIdx.x;
    const int wid = tid >> 6, L = tid & 63;
    float* xs = sX[wid];
    const float inv = 0.17677669529663687f; // 1/sqrt(32)

    const bool t0 = (L < 32);
    const int i1 = t0 ? 0 : (L - 32);
    const int v1 = i1 / 3, c1 = i1 - v1 * 3;
    const int i2 = L + 32;
    const int v2 = i2 / 3, c2 = i2 - v2 * 3;

    const int xb1 = t0 ? 0 : (32 + c1);
    const int xst1 = t0 ? 1 : 3;

    float wA[32], wB[32], wC[32], wD[32];
#pragma unroll
    for (int u = 0; u < 32; ++u) {
        wA[u] = t0 ? Wsc0[u * 32 + L] : Wsc1[u * 32 + v1];
        wB[u] = t0 ? Wl10[u * 32 + L] : Wl11[u * 32 + v1];
        wC[u] = Wsc1[u * 32 + v2];
        wD[u] = Wl11[u * 32 + v2];
    }

    const int stride = gridDim.x * 4;
    for (int n = blockIdx.x * 4 + wid; n < N; n += stride) {
        xs[L]      = x[(size_t)n * 128 + L];
        xs[64 + L] = x[(size_t)n * 128 + 64 + L];
        const float scale = inv * attr[n];
        float a0 = 0.f, a1 = 0.f, b0 = 0.f, b1 = 0.f;
#pragma unroll
        for (int u = 0; u < 32; ++u) {
            const float xv1 = xs[xb1 + u * xst1];
            const float xv2 = xs[32 + u * 3 + c2];
            a0 += xv1 * wA[u];
            a1 += xv1 * wB[u];
            b0 += xv2 * wC[u];
            b1 += xv2 * wD[u];
        }
        sc_out[(size_t)n * 128 + L]      = a0 * scale;
        sc_out[(size_t)n * 128 + 64 + L] = b0 * scale;
        y_out [(size_t)n * 128 + L]      = (_Float16)(a1 * scale);
        y_out [(size_t)n * 128 + 64 + L] = (_Float16)(b1 * scale);
    }
}

// ---------------------------------------------------------------------------
// CSR build: histogram -> 3-phase coalesced scan -> fill. (r17-r20 verified)
// ---------------------------------------------------------------------------
__global__ void hist_kernel(const int* __restrict__ edst, int* __restrict__ deg, int E)
{
    int i = blockIdx.x * blockDim.x + threadIdx.x;
    const int stride = gridDim.x * blockDim.x;
    for (; i < E; i += stride) atomicAdd(&deg[edst[i]], 1);
}

__global__ __launch_bounds__(256) void scanA_kernel(
    const int* __restrict__ deg, int* __restrict__ bsum, int N)
{
    __shared__ int red[256];
    const int t = threadIdx.x, b = blockIdx.x;
    const int base = b * SCAN_CH;
    int s = 0;
#pragma unroll
    for (int k = 0; k < 4; ++k) {
        const int idx = base + t + k * 256;
        if (idx < N) s += deg[idx];
    }
    red[t] = s;
    __syncthreads();
    for (int off = 128; off; off >>= 1) {
        if (t < off) red[t] += red[t + off];
        __syncthreads();
    }
    if (t == 0) bsum[b] = red[0];
}

__global__ __launch_bounds__(256) void scanB_kernel(
    const int* __restrict__ bsum, int* __restrict__ boff, int NB)
{
    __shared__ int s[256];
    const int t = threadIdx.x;
    const int v = (t < NB) ? bsum[t] : 0;
    s[t] = v;
    __syncthreads();
    for (int off = 1; off < 256; off <<= 1) {
        const int add = (t >= off) ? s[t - off] : 0;
        __syncthreads();
        s[t] += add;
        __syncthreads();
    }
    if (t < NB) boff[t] = s[t] - v;
}

__global__ __launch_bounds__(256) void scanC_kernel(
    const int* __restrict__ deg, const int* __restrict__ boff,
    int* __restrict__ row_ptr, int N)
{
    __shared__ int ts[256];
    const int t = threadIdx.x, b = blockIdx.x;
    const int base = b * SCAN_CH + t * 4;
    int d0 = 0, d1 = 0, d2 = 0, d3 = 0;
    if (base + 0 < N) d0 = deg[base + 0];
    if (base + 1 < N) d1 = deg[base + 1];
    if (base + 2 < N) d2 = deg[base + 2];
    if (base + 3 < N) d3 = deg[base + 3];
    const int tsum = d0 + d1 + d2 + d3;
    ts[t] = tsum;
    __syncthreads();
    for (int off = 1; off < 256; off <<= 1) {
        const int add = (t >= off) ? ts[t - off] : 0;
        __syncthreads();
        ts[t] += add;
        __syncthreads();
    }
    int run = boff[b] + ts[t] - tsum;
    if (base + 0 <= N) row_ptr[base + 0] = run;
    run += d0;
    if (base + 1 <= N) row_ptr[base + 1] = run;
    run += d1;
    if (base + 2 <= N) row_ptr[base + 2] = run;
    run += d2;
    if (base + 3 <= N) row_ptr[base + 3] = run;
}

__global__ void fill_kernel(
    const int* __restrict__ esrc, const int* __restrict__ edst,
    const float* __restrict__ esh,
    const int* __restrict__ row_ptr, int* __restrict__ cur,
    int* __restrict__ csr2edge, int* __restrict__ src_s, float4* __restrict__ sh_s,
    int E)
{
    int i = blockIdx.x * blockDim.x + threadIdx.x;
    const int stride = gridDim.x * blockDim.x;
    for (; i < E; i += stride) {
        const int d = edst[i];
        const int p = row_ptr[d] + atomicAdd(&cur[d], 1);
        csr2edge[p] = i;
        src_s[p] = esrc[i];
        sh_s[p] = *(const float4*)&esh[(size_t)i * 4];
    }
}

// ---------------------------------------------------------------------------
// Kernel B: edge MLP -> w, SOFTWARE-PIPELINED double-buffer version.
//  4 waves/block (256 thr), per-wave TWO 16x128 f16 buffers: loop body runs
//  phase2+store of batch k (buf k&1) adjacent to phase1 of batch k+1
//  (buf ~k&1) -- independent LDS streams the scheduler can interleave.
//  LDS = 32KB W2T + 32KB bufs = 64KB -> 2 blocks/CU, grid 512 all-resident.
// ---------------------------------------------------------------------------
__global__ __launch_bounds__(256) void edge_w_kernel(
    const float* __restrict__ escal, const int* __restrict__ csr2edge,
    const float* __restrict__ Wfc1, const float* __restrict__ Wfc2,
    _Float16* __restrict__ w_s, int E)
{
    __shared__ _Float16 sW2T[128 * 128];      // 32 KB, [col][k] swizzled
    __shared__ _Float16 sH[4][2][16 * 128];   // 2x4 KB per wave

    const int tid = threadIdx.x;
    const int wid = tid >> 6;              // wave 0..3
    const int l   = tid & 63;
    const int c16 = l & 15;
    const int kq  = l >> 4;

    _Float16* Hw0 = sH[wid][0];
    _Float16* Hw1 = sH[wid][1];

    {
        int* z2 = (int*)sW2T;
        for (int i = tid; i < 128 * 128 / 2; i += 256) z2[i] = 0;
    }
    __syncthreads();
    for (int i = tid; i < 100 * 128; i += 256) {
        const int k = i >> 7, col = i & 127;
        sW2T[col * 128 + (k ^ ((col & 7) << 3))] = (_Float16)Wfc2[i];
    }

    f16x8 bW1[7];
#pragma unroll
    for (int cb = 0; cb < 7; ++cb) {
        const int col = cb * 16 + c16;
#pragma unroll
        for (int j = 0; j < 8; ++j) {
            const int k = kq * 8 + j;
            bW1[cb][j] = (k < 10 && col < 100) ? (_Float16)Wfc1[k * 100 + col]
                                               : (_Float16)0.f;
        }
    }
    // zero pad cols 112..127 of both buffers
#pragma unroll
    for (int r = 0; r < 4; ++r) {
        const int row = kq * 4 + r;
        const int col = 112 + c16;
        Hw0[row * 128 + (col ^ ((row & 7) << 3))] = (_Float16)0.f;
        Hw1[row * 128 + (col ^ ((row & 7) << 3))] = (_Float16)0.f;
    }
    __syncthreads();   // W2T visible; no barriers after this

    const float inv_s10 = 0.31622776601683794f; // 1/sqrt(10)

    const int gw = blockIdx.x * 4 + wid;
    const int nw = gridDim.x * 4;
    const int step = nw * 16;

// gathered A1 fragment for batch starting at B (CSR slots)
#define LOAD_A1(DST, B)                                                       \
    {                                                                         \
        const int ge_ = (B) + c16;                                            \
        const int ee_ = (ge_ < E) ? csr2edge[ge_] : 0;                        \
        _Pragma("unroll")                                                     \
        for (int j_ = 0; j_ < 8; ++j_) {                                      \
            const int k_ = kq * 8 + j_;                                       \
            (DST)[j_] = (k_ < 10 && ge_ < E)                                  \
                        ? (_Float16)escal[(size_t)ee_ * 10 + k_]              \
                        : (_Float16)0.f;                                      \
        }                                                                     \
    }

// phase1: h = silu(A1@W1/sqrt10)*0.1 -> H (swizzled)
#define PHASE1(A1, H)                                                         \
    {                                                                         \
        _Pragma("unroll")                                                     \
        for (int cb_ = 0; cb_ < 7; ++cb_) {                                   \
            f32x4 z_ = {0.f, 0.f, 0.f, 0.f};                                  \
            z_ = __builtin_amdgcn_mfma_f32_16x16x32_f16((A1), bW1[cb_], z_, 0, 0, 0); \
            _Pragma("unroll")                                                 \
            for (int r_ = 0; r_ < 4; ++r_) {                                  \
                const int row_ = kq * 4 + r_;                                 \
                const int col_ = cb_ * 16 + c16;                              \
                const float h_ = silu_f(z_[r_] * inv_s10) * 0.1f;             \
                (H)[row_ * 128 + (col_ ^ ((row_ & 7) << 3))] = (_Float16)h_;  \
            }                                                                 \
        }                                                                     \
    }

// phase2: w = H@W2 (32 MFMA), stage into H, 4x coalesced stores for batch B
#define PHASE2_STORE(H, B)                                                    \
    {                                                                         \
        f32x4 ac0 = {0.f,0.f,0.f,0.f}, ac1 = {0.f,0.f,0.f,0.f};               \
        f32x4 ac2 = {0.f,0.f,0.f,0.f}, ac3 = {0.f,0.f,0.f,0.f};               \
        f32x4 ac4 = {0.f,0.f,0.f,0.f}, ac5 = {0.f,0.f,0.f,0.f};               \
        f32x4 ac6 = {0.f,0.f,0.f,0.f}, ac7 = {0.f,0.f,0.f,0.f};               \
        _Pragma("unroll")                                                     \
        for (int kk_ = 0; kk_ < 4; ++kk_) {                                   \
            const f16x8 a2_ = *(const f16x8*)&(H)[c16 * 128 +                 \
                                ((kk_ * 32 + kq * 8) ^ ((c16 & 7) << 3))];    \
            ac0 = __builtin_amdgcn_mfma_f32_16x16x32_f16(a2_, BFRAG(0, kk_), ac0, 0, 0, 0); \
            ac1 = __builtin_amdgcn_mfma_f32_16x16x32_f16(a2_, BFRAG(1, kk_), ac1, 0, 0, 0); \
            ac2 = __builtin_amdgcn_mfma_f32_16x16x32_f16(a2_, BFRAG(2, kk_), ac2, 0, 0, 0); \
            ac3 = __builtin_amdgcn_mfma_f32_16x16x32_f16(a2_, BFRAG(3, kk_), ac3, 0, 0, 0); \
            ac4 = __builtin_amdgcn_mfma_f32_16x16x32_f16(a2_, BFRAG(4, kk_), ac4, 0, 0, 0); \
            ac5 = __builtin_amdgcn_mfma_f32_16x16x32_f16(a2_, BFRAG(5, kk_), ac5, 0, 0, 0); \
            ac6 = __builtin_amdgcn_mfma_f32_16x16x32_f16(a2_, BFRAG(6, kk_), ac6, 0, 0, 0); \
            ac7 = __builtin_amdgcn_mfma_f32_16x16x32_f16(a2_, BFRAG(7, kk_), ac7, 0, 0, 0); \
        }                                                                     \
        STAGE_CB((H), 0, ac0) STAGE_CB((H), 1, ac1)                           \
        STAGE_CB((H), 2, ac2) STAGE_CB((H), 3, ac3)                           \
        STAGE_CB((H), 4, ac4) STAGE_CB((H), 5, ac5)                           \
        STAGE_CB((H), 6, ac6) STAGE_CB((H), 7, ac7)                           \
        _Pragma("unroll")                                                     \
        for (int i_ = 0; i_ < 4; ++i_) {                                      \
            const int e_ = i_ * 4 + (l >> 4);                                 \
            const int colb_ = (l & 15) * 8;                                   \
            const f16x8 v_ = *(const f16x8*)&(H)[e_ * 128 +                   \
                                (colb_ ^ ((e_ & 7) << 3))];                   \
            if ((B) + e_ < E)                                                 \
                *(f16x8*)&w_s[(size_t)((B) + e_) * 128 + colb_] = v_;         \
        }                                                                     \
    }

#define BFRAG(CB, KK) (*(const f16x8*)&sW2T[((CB) * 16 + c16) * 128 + \
                           (((KK) * 32 + kq * 8) ^ ((c16 & 7) << 3))])
#define STAGE_CB(H, CB, ACC)                                                  \
        {                                                                     \
            _Pragma("unroll")                                                 \
            for (int r_ = 0; r_ < 4; ++r_) {                                  \
                const int row_ = kq * 4 + r_;                                 \
                const int col_ = (CB) * 16 + c16;                             \
                (H)[row_ * 128 + (col_ ^ ((row_ & 7) << 3))] = (_Float16)(ACC)[r_]; \
            }                                                                 \
        }

    int base = gw * 16;
    if (base >= E) return;

    // prologue: fill buffer 0 with batch 0's h; prefetch batch 1's A1
    f16x8 a1;
    LOAD_A1(a1, base)
    PHASE1(a1, Hw0)
    LOAD_A1(a1, base + step)

    int par = 0;
    for (; base + step < E; base += step, par ^= 1) {
        _Float16* Hc = par ? Hw1 : Hw0;   // holds batch k's h
        _Float16* Hn = par ? Hw0 : Hw1;   // will hold batch k+1's h
        PHASE2_STORE(Hc, base)            // consume batch k
        PHASE1(a1, Hn)                    // produce batch k+1 (independent)
        LOAD_A1(a1, base + 2 * step)      // prefetch batch k+2
    }
    {
        _Float16* Hc = par ? Hw1 : Hw0;
        PHASE2_STORE(Hc, base)            // epilogue: last batch
    }

#undef LOAD_A1
#undef PHASE1
#undef PHASE2_STORE
#undef BFRAG
#undef STAGE_CB
}

// ---------------------------------------------------------------------------
// Kernel C: gather + mean + fused post. (r20-verified: 2-deep edge loop,
// transposed padded epilogue weights)
// ---------------------------------------------------------------------------
__global__ __launch_bounds__(256) void gather_post_kernel(
    const _Float16* __restrict__ w_s, const int* __restrict__ src_s,
    const float4* __restrict__ sh_s, const int* __restrict__ row_ptr,
    const _Float16* __restrict__ y, const float* __restrict__ attr,
    const float* __restrict__ Wl20, const float* __restrict__ Wl21,
    const float* __restrict__ Walpha,
    float* __restrict__ out, int N)
{
    __shared__ float sW0T[32 * 68];   // [o][u] padded
    __shared__ float sW1T[32 * 68];   // [o][u] padded
    __shared__ float sWa[64];
    __shared__ float sMid[4][256];    // per-wave: [mid0(64) | midT(3x64)]

    const int tid = threadIdx.x;
    for (int i = tid; i < 64 * 32; i += 256) {
        const int u = i >> 5, o = i & 31;
        sW0T[o * 68 + u] = Wl20[i];
        sW1T[o * 68 + u] = Wl21[i];
    }
    if (tid < 64) sWa[tid] = Walpha[tid];
    __syncthreads();   // only barrier; node loop is barrier-free

    const int wid = tid >> 6;
    const int L   = tid & 63;
    const bool hi = (L >= 32);
    const int u   = L & 31;

    const int wAi = hi ? 32 + u : u;
    const int wBi = hi ? 96 + u : 64 + u;
    const int yi0 = hi ? 32 + 3 * u + 0 : u;
    const int yi1 = hi ? 32 + 3 * u + 1 : u;
    const int yi2 = hi ? 32 + 3 * u + 2 : u;
    const float mulA = hi ? 0.5773502691896258f : 1.0f;   // 1/sqrt(3) on m11

    const int o1m = L - 32;
    const int v1 = hi ? o1m / 3 : 0;
    const int c1 = hi ? o1m - v1 * 3 : 0;
    const int o2m = L + 32;
    const int v2 = o2m / 3;
    const int c2 = o2m - v2 * 3;
    const float* wrow1 = hi ? (sW1T + v1 * 68) : (sW0T + L * 68);
    const float* wrow2 = sW1T + v2 * 68;

    float* midw = &sMid[wid][0];
    const float* msrc1c = hi ? (midw + 64 + c1 * 64) : midw;
    const float* msrc2c = midw + 64 + c2 * 64;

#define ACC_EDGE(sh, wAv, wBv, q0, q1, q2) do {                        \
        const float sA0 = hi ? (sh).y : (sh).x;                        \
        const float sA1 = hi ? (sh).z : 0.f;                           \
        const float sA2 = hi ? (sh).w : 0.f;                           \
        const float b1s = hi ? (sh).x : (sh).y;                        \
        const float b2s = hi ? (sh).x : (sh).z;                        \
        const float b3s = hi ? (sh).x : (sh).w;                        \
        accA += (wAv) * mulA * ((q0) * sA0 + (q1) * sA1 + (q2) * sA2); \
        acc1 += (wBv) * (q0) * b1s;                                    \
        acc2 += (wBv) * (q1) * b2s;                                    \
        acc3 += (wBv) * (q2) * b3s;                                    \
    } while (0)

    const int waves_glob = gridDim.x * 4;
    for (int n = blockIdx.x * 4 + wid; n < N; n += waves_glob) {
        const int jlo = row_ptr[n];
        const int jhi = row_ptr[n + 1];
        const int deg = jhi - jlo;
        if (deg <= 0) continue;

        float accA = 0.f, acc1 = 0.f, acc2 = 0.f, acc3 = 0.f;

        int j = jlo;
        for (; j + 2 <= jhi; j += 2) {
            const int sa = src_s[j];
            const int sb = src_s[j + 1];
            const float4 shA = sh_s[j];
            const float4 shB = sh_s[j + 1];
            const _Float16* wra = w_s + (size_t)j * 128;
            const _Float16* wrb = wra + 128;
            const _Float16* yra = y + (size_t)sa * 128;
            const _Float16* yrb = y + (size_t)sb * 128;
            const float wAa = (float)wra[wAi], wBa = (float)wra[wBi];
            const float qa0 = (float)yra[yi0], qa1 = (float)yra[yi1], qa2 = (float)yra[yi2];
            const float wAb = (float)wrb[wAi], wBb = (float)wrb[wBi];
            const float qb0 = (float)yrb[yi0], qb1 = (float)yrb[yi1], qb2 = (float)yrb[yi2];
            ACC_EDGE(shA, wAa, wBa, qa0, qa1, qa2);
            ACC_EDGE(shB, wAb, wBb, qb0, qb1, qb2);
        }
        if (j < jhi) {
            const int sa = src_s[j];
            const float4 shA = sh_s[j];
            const _Float16* wra = w_s + (size_t)j * 128;
            const _Float16* yra = y + (size_t)sa * 128;
            const float wAa = (float)wra[wAi], wBa = (float)wra[wBi];
            const float qa0 = (float)yra[yi0], qa1 = (float)yra[yi1], qa2 = (float)yra[yi2];
            ACC_EDGE(shA, wAa, wBa, qa0, qa1, qa2);
        }

        const float rdeg = 1.0f / (float)deg;
        const float a = attr[n];

        float term = accA * rdeg * sWa[L];
#pragma unroll
        for (int off = 32; off; off >>= 1) term += __shfl_xor(term, off);
        const float alpha = term * 0.125f * a;

        midw[L]            = accA * rdeg;
        midw[64 + L]       = acc1 * rdeg;
        midw[128 + L]      = acc2 * rdeg;
        midw[192 + L]      = acc3 * rdeg;

        float cv1 = 0.f, cv2 = 0.f;
#pragma unroll
        for (int kk = 0; kk < 16; ++kk) {
            const float4 m1 = *(const float4*)&msrc1c[4 * kk];
            const float4 m2 = *(const float4*)&msrc2c[4 * kk];
            const float4 w1 = *(const float4*)&wrow1[4 * kk];
            const float4 w2 = *(const float4*)&wrow2[4 * kk];
            cv1 += m1.x * w1.x + m1.y * w1.y + m1.z * w1.z + m1.w * w1.w;
            cv2 += m2.x * w2.x + m2.y * w2.y + m2.z * w2.z + m2.w * w2.w;
        }
        const float f = alpha * 0.125f * a;
        const size_t ob = (size_t)n * 128;
        out[ob + L]      += f * cv1;
        out[ob + 64 + L] += f * cv2;
    }
#undef ACC_EDGE
}

extern "C" void kernel_launch(void* const* d_in, const int* in_sizes, int n_in,
                              void* d_out, int out_size, void* d_ws, size_t ws_size,
                              hipStream_t stream)
{
    const float* x      = (const float*)d_in[0];
    const float* attr   = (const float*)d_in[1];
    const int*   esrc   = (const int*)  d_in[2];
    const int*   edst   = (const int*)  d_in[3];
    const float* esh    = (const float*)d_in[4];
    const float* escal  = (const float*)d_in[5];
    const float* Wfc1   = (const float*)d_in[6];
    const float* Wfc2   = (const float*)d_in[7];
    const float* Wsc0   = (const float*)d_in[8];
    const float* Wsc1   = (const float*)d_in[9];
    const float* Wl10   = (const float*)d_in[10];
    const float* Wl11   = (const float*)d_in[11];
    const float* Wl20   = (const float*)d_in[12];
    const float* Wl21   = (const float*)d_in[13];
    const float* Walpha = (const float*)d_in[14];

    const int N = in_sizes[1];
    const int E = in_sizes[2];
    float* out = (float*)d_out;

    // ws: y(f16) | row_ptr | deg | cur | bsum | boff | csr2edge | src_s |
    //     [align16] sh_s | w_s
    char* p = (char*)d_ws;
    _Float16* y   = (_Float16*)p; p += (size_t)N * 128 * sizeof(_Float16);
    int* row_ptr  = (int*)p;      p += (size_t)(N + 1) * sizeof(int);
    int* deg      = (int*)p;      p += (size_t)N * sizeof(int);
    int* cur      = (int*)p;      p += (size_t)N * sizeof(int);
    int* bsum     = (int*)p;      p += 256 * sizeof(int);
    int* boff     = (int*)p;      p += 256 * sizeof(int);
    int* csr2edge = (int*)p;      p += (size_t)E * sizeof(int);
    int* src_s    = (int*)p;      p += (size_t)E * sizeof(int);
    p = (char*)(((uintptr_t)p + 15) & ~(uintptr_t)15);
    float4* sh_s  = (float4*)p;   p += (size_t)E * sizeof(float4);
    _Float16* w_s = (_Float16*)p;

    const int NB = (N + SCAN_CH) / SCAN_CH;   // covers row_ptr[N]

    hipMemsetAsync(deg, 0, (size_t)2 * N * sizeof(int), stream);

    node_pre_kernel<<<1024, 256, 0, stream>>>(x, attr, Wsc0, Wsc1, Wl10, Wl11,
                                              out, y, N);
    hist_kernel<<<512, 256, 0, stream>>>(edst, deg, E);
    scanA_kernel<<<NB, 256, 0, stream>>>(deg, bsum, N);
    scanB_kernel<<<1, 256, 0, stream>>>(bsum, boff, NB);
    scanC_kernel<<<NB, 256, 0, stream>>>(deg, boff, row_ptr, N);
    fill_kernel<<<512, 256, 0, stream>>>(esrc, edst, esh, row_ptr, cur,
                                         csr2edge, src_s, sh_s, E);
    edge_w_kernel<<<512, 256, 0, stream>>>(escal, csr2edge, Wfc1, Wfc2, w_s, E);
    gather_post_kernel<<<4096, 256, 0, stream>>>(w_s, src_s, sh_s, row_ptr,
                                                 y, attr, Wl20, Wl21, Walpha,
                                                 out, N);
}

// Round 22
// 231.639 us; speedup vs baseline: 1.1662x; 1.1662x over previous
//
#include <hip/hip_runtime.h>
#include <hip/hip_bf16.h>

#define MUL 32
#define SCAN_CH 1024

typedef _Float16 f16x8 __attribute__((ext_vector_type(8)));
typedef float f32x4 __attribute__((ext_vector_type(4)));

static __device__ __forceinline__ float silu_f(float z) {
    return z / (1.0f + __expf(-z));
}

// ---------------------------------------------------------------------------
// Kernel A (MERGED): blocks [0,1024) = node_pre (r14-r20 verified body,
// wave-per-node, barrier-free); blocks [1024,1536) = hist. Independent work,
// one dispatch.
// ---------------------------------------------------------------------------
__global__ __launch_bounds__(256) void pre_hist_kernel(
    const float* __restrict__ x, const float* __restrict__ attr,
    const float* __restrict__ Wsc0, const float* __restrict__ Wsc1,
    const float* __restrict__ Wl10, const float* __restrict__ Wl11,
    float* __restrict__ sc_out, _Float16* __restrict__ y_out, int N,
    const int* __restrict__ edst, int* __restrict__ deg, int E)
{
    __shared__ float sX[4][128];
    const int tid = threadIdx.x;

    if (blockIdx.x >= 1024) {
        // ---- hist part ----
        const int b = blockIdx.x - 1024;
        int i = b * 256 + tid;
        const int stride = 512 * 256;
        for (; i < E; i += stride) atomicAdd(&deg[edst[i]], 1);
        return;
    }

    // ---- node_pre part ----
    const int wid = tid >> 6, L = tid & 63;
    float* xs = sX[wid];
    const float inv = 0.17677669529663687f; // 1/sqrt(32)

    const bool t0 = (L < 32);
    const int i1 = t0 ? 0 : (L - 32);
    const int v1 = i1 / 3, c1 = i1 - v1 * 3;
    const int i2 = L + 32;
    const int v2 = i2 / 3, c2 = i2 - v2 * 3;

    const int xb1 = t0 ? 0 : (32 + c1);
    const int xst1 = t0 ? 1 : 3;

    float wA[32], wB[32], wC[32], wD[32];
#pragma unroll
    for (int u = 0; u < 32; ++u) {
        wA[u] = t0 ? Wsc0[u * 32 + L] : Wsc1[u * 32 + v1];
        wB[u] = t0 ? Wl10[u * 32 + L] : Wl11[u * 32 + v1];
        wC[u] = Wsc1[u * 32 + v2];
        wD[u] = Wl11[u * 32 + v2];
    }

    const int stride = 1024 * 4;
    for (int n = blockIdx.x * 4 + wid; n < N; n += stride) {
        xs[L]      = x[(size_t)n * 128 + L];
        xs[64 + L] = x[(size_t)n * 128 + 64 + L];
        const float scale = inv * attr[n];
        float a0 = 0.f, a1 = 0.f, b0 = 0.f, b1 = 0.f;
#pragma unroll
        for (int u = 0; u < 32; ++u) {
            const float xv1 = xs[xb1 + u * xst1];
            const float xv2 = xs[32 + u * 3 + c2];
            a0 += xv1 * wA[u];
            a1 += xv1 * wB[u];
            b0 += xv2 * wC[u];
            b1 += xv2 * wD[u];
        }
        sc_out[(size_t)n * 128 + L]      = a0 * scale;
        sc_out[(size_t)n * 128 + 64 + L] = b0 * scale;
        y_out [(size_t)n * 128 + L]      = (_Float16)(a1 * scale);
        y_out [(size_t)n * 128 + 64 + L] = (_Float16)(b1 * scale);
    }
}

// ---------------------------------------------------------------------------
// CSR build: scanA (block partials) -> scanC2 (inline 256-wide scan of
// partials + apply). (3-phase scan verified r17-r20; scanB now inlined)
// ---------------------------------------------------------------------------
__global__ __launch_bounds__(256) void scanA_kernel(
    const int* __restrict__ deg, int* __restrict__ bsum, int N)
{
    __shared__ int red[256];
    const int t = threadIdx.x, b = blockIdx.x;
    const int base = b * SCAN_CH;
    int s = 0;
#pragma unroll
    for (int k = 0; k < 4; ++k) {
        const int idx = base + t + k * 256;
        if (idx < N) s += deg[idx];
    }
    red[t] = s;
    __syncthreads();
    for (int off = 128; off; off >>= 1) {
        if (t < off) red[t] += red[t + off];
        __syncthreads();
    }
    if (t == 0) bsum[b] = red[0];
}

__global__ __launch_bounds__(256) void scanC2_kernel(
    const int* __restrict__ deg, const int* __restrict__ bsum,
    int* __restrict__ row_ptr, int N, int NB)
{
    __shared__ int sb[256];
    __shared__ int ts[256];
    const int t = threadIdx.x, b = blockIdx.x;

    // inline scanB: inclusive scan of bsum (NB <= 256)
    sb[t] = (t < NB) ? bsum[t] : 0;
    __syncthreads();
    for (int off = 1; off < 256; off <<= 1) {
        const int add = (t >= off) ? sb[t - off] : 0;
        __syncthreads();
        sb[t] += add;
        __syncthreads();
    }
    const int boffb = (b == 0) ? 0 : sb[b - 1];   // exclusive prefix at block b
    __syncthreads();

    const int base = b * SCAN_CH + t * 4;
    int d0 = 0, d1 = 0, d2 = 0, d3 = 0;
    if (base + 0 < N) d0 = deg[base + 0];
    if (base + 1 < N) d1 = deg[base + 1];
    if (base + 2 < N) d2 = deg[base + 2];
    if (base + 3 < N) d3 = deg[base + 3];
    const int tsum = d0 + d1 + d2 + d3;
    ts[t] = tsum;
    __syncthreads();
    for (int off = 1; off < 256; off <<= 1) {
        const int add = (t >= off) ? ts[t - off] : 0;
        __syncthreads();
        ts[t] += add;
        __syncthreads();
    }
    int run = boffb + ts[t] - tsum;
    if (base + 0 <= N) row_ptr[base + 0] = run;
    run += d0;
    if (base + 1 <= N) row_ptr[base + 1] = run;
    run += d1;
    if (base + 2 <= N) row_ptr[base + 2] = run;
    run += d2;
    if (base + 3 <= N) row_ptr[base + 3] = run;
}

__global__ void fill_kernel(
    const int* __restrict__ esrc, const int* __restrict__ edst,
    const float* __restrict__ esh,
    const int* __restrict__ row_ptr, int* __restrict__ cur,
    int* __restrict__ csr2edge, int* __restrict__ src_s, float4* __restrict__ sh_s,
    int E)
{
    int i = blockIdx.x * blockDim.x + threadIdx.x;
    const int stride = gridDim.x * blockDim.x;
    for (; i < E; i += stride) {
        const int d = edst[i];
        const int p = row_ptr[d] + atomicAdd(&cur[d], 1);
        csr2edge[p] = i;
        src_s[p] = esrc[i];
        sh_s[p] = *(const float4*)&esh[(size_t)i * 4];
    }
}

// ---------------------------------------------------------------------------
// Kernel B: edge MLP -> w (f16, CSR-slot order, sequential stores).
// r20-EXACT (88 us verified): 512 threads, 8 waves share W2T, 2 blocks/CU,
// grid 512 all-resident, single-buffer per-wave h, 2-deep escal prefetch.
// ---------------------------------------------------------------------------
__global__ __launch_bounds__(512) void edge_w_kernel(
    const float* __restrict__ escal, const int* __restrict__ csr2edge,
    const float* __restrict__ Wfc1, const float* __restrict__ Wfc2,
    _Float16* __restrict__ w_s, int E)
{
    __shared__ _Float16 sW2T[128 * 128];   // 32 KB, [col][k] swizzled
    __shared__ _Float16 sH[8][16 * 128];   // 4 KB per wave (h, then w staging)

    const int tid = threadIdx.x;
    const int wid = tid >> 6;              // wave 0..7
    const int l   = tid & 63;
    const int c16 = l & 15;
    const int kq  = l >> 4;

    _Float16* Hw = sH[wid];

    {
        int* z2 = (int*)sW2T;
        for (int i = tid; i < 128 * 128 / 2; i += 512) z2[i] = 0;
    }
    __syncthreads();
    for (int i = tid; i < 100 * 128; i += 512) {
        const int k = i >> 7, col = i & 127;
        sW2T[col * 128 + (k ^ ((col & 7) << 3))] = (_Float16)Wfc2[i];
    }

    f16x8 bW1[7];
#pragma unroll
    for (int cb = 0; cb < 7; ++cb) {
        const int col = cb * 16 + c16;
#pragma unroll
        for (int j = 0; j < 8; ++j) {
            const int k = kq * 8 + j;
            bW1[cb][j] = (k < 10 && col < 100) ? (_Float16)Wfc1[k * 100 + col]
                                               : (_Float16)0.f;
        }
    }
#pragma unroll
    for (int r = 0; r < 4; ++r) {
        const int row = kq * 4 + r;
        const int col = 112 + c16;
        Hw[row * 128 + (col ^ ((row & 7) << 3))] = (_Float16)0.f;
    }
    __syncthreads();   // W2T visible to all waves; no barriers after this

    const float inv_s10 = 0.31622776601683794f; // 1/sqrt(10)

    const int gw = blockIdx.x * 8 + wid;
    const int nw = gridDim.x * 8;
    const int step = nw * 16;

    int base = gw * 16;
    f16x8 a1;
    {
        const int ge = base + c16;
        const int ee = (ge < E) ? csr2edge[ge] : 0;
#pragma unroll
        for (int j = 0; j < 8; ++j) {
            const int k = kq * 8 + j;
            a1[j] = (k < 10 && ge < E) ? (_Float16)escal[(size_t)ee * 10 + k]
                                       : (_Float16)0.f;
        }
    }

    for (; base < E; base += step) {
#pragma unroll
        for (int cb = 0; cb < 7; ++cb) {
            f32x4 z = {0.f, 0.f, 0.f, 0.f};
            z = __builtin_amdgcn_mfma_f32_16x16x32_f16(a1, bW1[cb], z, 0, 0, 0);
#pragma unroll
            for (int r = 0; r < 4; ++r) {
                const int row = kq * 4 + r;
                const int col = cb * 16 + c16;
                const float h = silu_f(z[r] * inv_s10) * 0.1f;
                Hw[row * 128 + (col ^ ((row & 7) << 3))] = (_Float16)h;
            }
        }

        f16x8 a1n;
        {
            const int ge = base + step + c16;
            const int ee = (ge < E) ? csr2edge[ge] : 0;
#pragma unroll
            for (int j = 0; j < 8; ++j) {
                const int k = kq * 8 + j;
                a1n[j] = (k < 10 && ge < E)
                         ? (_Float16)escal[(size_t)ee * 10 + k]
                         : (_Float16)0.f;
            }
        }

        f32x4 acc0 = {0.f,0.f,0.f,0.f}, acc1 = {0.f,0.f,0.f,0.f};
        f32x4 acc2 = {0.f,0.f,0.f,0.f}, acc3 = {0.f,0.f,0.f,0.f};
        f32x4 acc4 = {0.f,0.f,0.f,0.f}, acc5 = {0.f,0.f,0.f,0.f};
        f32x4 acc6 = {0.f,0.f,0.f,0.f}, acc7 = {0.f,0.f,0.f,0.f};
#pragma unroll
        for (int kk = 0; kk < 4; ++kk) {
            const f16x8 a2 = *(const f16x8*)&Hw[c16 * 128 +
                                ((kk * 32 + kq * 8) ^ ((c16 & 7) << 3))];
#define BFRAG(CB) (*(const f16x8*)&sW2T[((CB) * 16 + c16) * 128 + \
                       ((kk * 32 + kq * 8) ^ ((c16 & 7) << 3))])
            acc0 = __builtin_amdgcn_mfma_f32_16x16x32_f16(a2, BFRAG(0), acc0, 0, 0, 0);
            acc1 = __builtin_amdgcn_mfma_f32_16x16x32_f16(a2, BFRAG(1), acc1, 0, 0, 0);
            acc2 = __builtin_amdgcn_mfma_f32_16x16x32_f16(a2, BFRAG(2), acc2, 0, 0, 0);
            acc3 = __builtin_amdgcn_mfma_f32_16x16x32_f16(a2, BFRAG(3), acc3, 0, 0, 0);
            acc4 = __builtin_amdgcn_mfma_f32_16x16x32_f16(a2, BFRAG(4), acc4, 0, 0, 0);
            acc5 = __builtin_amdgcn_mfma_f32_16x16x32_f16(a2, BFRAG(5), acc5, 0, 0, 0);
            acc6 = __builtin_amdgcn_mfma_f32_16x16x32_f16(a2, BFRAG(6), acc6, 0, 0, 0);
            acc7 = __builtin_amdgcn_mfma_f32_16x16x32_f16(a2, BFRAG(7), acc7, 0, 0, 0);
#undef BFRAG
        }

#define STAGE_CB(CB, ACC)                                                     \
        {                                                                     \
            _Pragma("unroll")                                                 \
            for (int r = 0; r < 4; ++r) {                                     \
                const int row = kq * 4 + r;                                   \
                const int col = (CB) * 16 + c16;                              \
                Hw[row * 128 + (col ^ ((row & 7) << 3))] = (_Float16)(ACC)[r];\
            }                                                                 \
        }
        STAGE_CB(0, acc0) STAGE_CB(1, acc1) STAGE_CB(2, acc2) STAGE_CB(3, acc3)
        STAGE_CB(4, acc4) STAGE_CB(5, acc5) STAGE_CB(6, acc6) STAGE_CB(7, acc7)
#undef STAGE_CB

#pragma unroll
        for (int i = 0; i < 4; ++i) {
            const int e = i * 4 + (l >> 4);
            const int colb = (l & 15) * 8;
            const f16x8 v = *(const f16x8*)&Hw[e * 128 +
                                (colb ^ ((e & 7) << 3))];
            if (base + e < E)
                *(f16x8*)&w_s[(size_t)(base + e) * 128 + colb] = v;
        }

        a1 = a1n;
    }
}

// ---------------------------------------------------------------------------
// Kernel C: gather + mean + fused post. (r20-verified: 2-deep edge loop,
// transposed padded epilogue weights)
// ---------------------------------------------------------------------------
__global__ __launch_bounds__(256) void gather_post_kernel(
    const _Float16* __restrict__ w_s, const int* __restrict__ src_s,
    const float4* __restrict__ sh_s, const int* __restrict__ row_ptr,
    const _Float16* __restrict__ y, const float* __restrict__ attr,
    const float* __restrict__ Wl20, const float* __restrict__ Wl21,
    const float* __restrict__ Walpha,
    float* __restrict__ out, int N)
{
    __shared__ float sW0T[32 * 68];   // [o][u] padded
    __shared__ float sW1T[32 * 68];   // [o][u] padded
    __shared__ float sWa[64];
    __shared__ float sMid[4][256];    // per-wave: [mid0(64) | midT(3x64)]

    const int tid = threadIdx.x;
    for (int i = tid; i < 64 * 32; i += 256) {
        const int u = i >> 5, o = i & 31;
        sW0T[o * 68 + u] = Wl20[i];
        sW1T[o * 68 + u] = Wl21[i];
    }
    if (tid < 64) sWa[tid] = Walpha[tid];
    __syncthreads();   // only barrier; node loop is barrier-free

    const int wid = tid >> 6;
    const int L   = tid & 63;
    const bool hi = (L >= 32);
    const int u   = L & 31;

    const int wAi = hi ? 32 + u : u;
    const int wBi = hi ? 96 + u : 64 + u;
    const int yi0 = hi ? 32 + 3 * u + 0 : u;
    const int yi1 = hi ? 32 + 3 * u + 1 : u;
    const int yi2 = hi ? 32 + 3 * u + 2 : u;
    const float mulA = hi ? 0.5773502691896258f : 1.0f;   // 1/sqrt(3) on m11

    const int o1m = L - 32;
    const int v1 = hi ? o1m / 3 : 0;
    const int c1 = hi ? o1m - v1 * 3 : 0;
    const int o2m = L + 32;
    const int v2 = o2m / 3;
    const int c2 = o2m - v2 * 3;
    const float* wrow1 = hi ? (sW1T + v1 * 68) : (sW0T + L * 68);
    const float* wrow2 = sW1T + v2 * 68;

    float* midw = &sMid[wid][0];
    const float* msrc1c = hi ? (midw + 64 + c1 * 64) : midw;
    const float* msrc2c = midw + 64 + c2 * 64;

#define ACC_EDGE(sh, wAv, wBv, q0, q1, q2) do {                        \
        const float sA0 = hi ? (sh).y : (sh).x;                        \
        const float sA1 = hi ? (sh).z : 0.f;                           \
        const float sA2 = hi ? (sh).w : 0.f;                           \
        const float b1s = hi ? (sh).x : (sh).y;                        \
        const float b2s = hi ? (sh).x : (sh).z;                        \
        const float b3s = hi ? (sh).x : (sh).w;                        \
        accA += (wAv) * mulA * ((q0) * sA0 + (q1) * sA1 + (q2) * sA2); \
        acc1 += (wBv) * (q0) * b1s;                                    \
        acc2 += (wBv) * (q1) * b2s;                                    \
        acc3 += (wBv) * (q2) * b3s;                                    \
    } while (0)

    const int waves_glob = gridDim.x * 4;
    for (int n = blockIdx.x * 4 + wid; n < N; n += waves_glob) {
        const int jlo = row_ptr[n];
        const int jhi = row_ptr[n + 1];
        const int deg = jhi - jlo;
        if (deg <= 0) continue;

        float accA = 0.f, acc1 = 0.f, acc2 = 0.f, acc3 = 0.f;

        int j = jlo;
        for (; j + 2 <= jhi; j += 2) {
            const int sa = src_s[j];
            const int sb = src_s[j + 1];
            const float4 shA = sh_s[j];
            const float4 shB = sh_s[j + 1];
            const _Float16* wra = w_s + (size_t)j * 128;
            const _Float16* wrb = wra + 128;
            const _Float16* yra = y + (size_t)sa * 128;
            const _Float16* yrb = y + (size_t)sb * 128;
            const float wAa = (float)wra[wAi], wBa = (float)wra[wBi];
            const float qa0 = (float)yra[yi0], qa1 = (float)yra[yi1], qa2 = (float)yra[yi2];
            const float wAb = (float)wrb[wAi], wBb = (float)wrb[wBi];
            const float qb0 = (float)yrb[yi0], qb1 = (float)yrb[yi1], qb2 = (float)yrb[yi2];
            ACC_EDGE(shA, wAa, wBa, qa0, qa1, qa2);
            ACC_EDGE(shB, wAb, wBb, qb0, qb1, qb2);
        }
        if (j < jhi) {
            const int sa = src_s[j];
            const float4 shA = sh_s[j];
            const _Float16* wra = w_s + (size_t)j * 128;
            const _Float16* yra = y + (size_t)sa * 128;
            const float wAa = (float)wra[wAi], wBa = (float)wra[wBi];
            const float qa0 = (float)yra[yi0], qa1 = (float)yra[yi1], qa2 = (float)yra[yi2];
            ACC_EDGE(shA, wAa, wBa, qa0, qa1, qa2);
        }

        const float rdeg = 1.0f / (float)deg;
        const float a = attr[n];

        float term = accA * rdeg * sWa[L];
#pragma unroll
        for (int off = 32; off; off >>= 1) term += __shfl_xor(term, off);
        const float alpha = term * 0.125f * a;

        midw[L]            = accA * rdeg;
        midw[64 + L]       = acc1 * rdeg;
        midw[128 + L]      = acc2 * rdeg;
        midw[192 + L]      = acc3 * rdeg;

        float cv1 = 0.f, cv2 = 0.f;
#pragma unroll
        for (int kk = 0; kk < 16; ++kk) {
            const float4 m1 = *(const float4*)&msrc1c[4 * kk];
            const float4 m2 = *(const float4*)&msrc2c[4 * kk];
            const float4 w1 = *(const float4*)&wrow1[4 * kk];
            const float4 w2 = *(const float4*)&wrow2[4 * kk];
            cv1 += m1.x * w1.x + m1.y * w1.y + m1.z * w1.z + m1.w * w1.w;
            cv2 += m2.x * w2.x + m2.y * w2.y + m2.z * w2.z + m2.w * w2.w;
        }
        const float f = alpha * 0.125f * a;
        const size_t ob = (size_t)n * 128;
        out[ob + L]      += f * cv1;
        out[ob + 64 + L] += f * cv2;
    }
#undef ACC_EDGE
}

extern "C" void kernel_launch(void* const* d_in, const int* in_sizes, int n_in,
                              void* d_out, int out_size, void* d_ws, size_t ws_size,
                              hipStream_t stream)
{
    const float* x      = (const float*)d_in[0];
    const float* attr   = (const float*)d_in[1];
    const int*   esrc   = (const int*)  d_in[2];
    const int*   edst   = (const int*)  d_in[3];
    const float* esh    = (const float*)d_in[4];
    const float* escal  = (const float*)d_in[5];
    const float* Wfc1   = (const float*)d_in[6];
    const float* Wfc2   = (const float*)d_in[7];
    const float* Wsc0   = (const float*)d_in[8];
    const float* Wsc1   = (const float*)d_in[9];
    const float* Wl10   = (const float*)d_in[10];
    const float* Wl11   = (const float*)d_in[11];
    const float* Wl20   = (const float*)d_in[12];
    const float* Wl21   = (const float*)d_in[13];
    const float* Walpha = (const float*)d_in[14];

    const int N = in_sizes[1];
    const int E = in_sizes[2];
    float* out = (float*)d_out;

    // ws: y(f16) | row_ptr | deg | cur | bsum | csr2edge | src_s |
    //     [align16] sh_s | w_s
    char* p = (char*)d_ws;
    _Float16* y   = (_Float16*)p; p += (size_t)N * 128 * sizeof(_Float16);
    int* row_ptr  = (int*)p;      p += (size_t)(N + 1) * sizeof(int);
    int* deg      = (int*)p;      p += (size_t)N * sizeof(int);
    int* cur      = (int*)p;      p += (size_t)N * sizeof(int);
    int* bsum     = (int*)p;      p += 256 * sizeof(int);
    int* csr2edge = (int*)p;      p += (size_t)E * sizeof(int);
    int* src_s    = (int*)p;      p += (size_t)E * sizeof(int);
    p = (char*)(((uintptr_t)p + 15) & ~(uintptr_t)15);
    float4* sh_s  = (float4*)p;   p += (size_t)E * sizeof(float4);
    _Float16* w_s = (_Float16*)p;

    const int NB = (N + SCAN_CH) / SCAN_CH;   // covers row_ptr[N]

    hipMemsetAsync(deg, 0, (size_t)2 * N * sizeof(int), stream);

    pre_hist_kernel<<<1536, 256, 0, stream>>>(x, attr, Wsc0, Wsc1, Wl10, Wl11,
                                              out, y, N, edst, deg, E);
    scanA_kernel<<<NB, 256, 0, stream>>>(deg, bsum, N);
    scanC2_kernel<<<NB, 256, 0, stream>>>(deg, bsum, row_ptr, N, NB);
    fill_kernel<<<512, 256, 0, stream>>>(esrc, edst, esh, row_ptr, cur,
                                         csr2edge, src_s, sh_s, E);
    edge_w_kernel<<<512, 512, 0, stream>>>(escal, csr2edge, Wfc1, Wfc2, w_s, E);
    gather_post_kernel<<<4096, 256, 0, stream>>>(w_s, src_s, sh_s, row_ptr,
                                                 y, attr, Wl20, Wl21, Walpha,
                                                 out, N);
}

// Round 23
// 231.276 us; speedup vs baseline: 1.1680x; 1.0016x over previous
//
#include <hip/hip_runtime.h>
#include <hip/hip_bf16.h>

#define MUL 32
#define SCAN_CH 1024

typedef _Float16 f16x8 __attribute__((ext_vector_type(8)));
typedef float f32x4 __attribute__((ext_vector_type(4)));

static __device__ __forceinline__ float silu_f(float z) {
    return z / (1.0f + __expf(-z));
}

// ---------------------------------------------------------------------------
// Kernel A (MERGED): blocks [0,1024) = node_pre; blocks [1024,1536) = hist.
// (r22-verified)
// ---------------------------------------------------------------------------
__global__ __launch_bounds__(256) void pre_hist_kernel(
    const float* __restrict__ x, const float* __restrict__ attr,
    const float* __restrict__ Wsc0, const float* __restrict__ Wsc1,
    const float* __restrict__ Wl10, const float* __restrict__ Wl11,
    float* __restrict__ sc_out, _Float16* __restrict__ y_out, int N,
    const int* __restrict__ edst, int* __restrict__ deg, int E)
{
    __shared__ float sX[4][128];
    const int tid = threadIdx.x;

    if (blockIdx.x >= 1024) {
        const int b = blockIdx.x - 1024;
        int i = b * 256 + tid;
        const int stride = 512 * 256;
        for (; i < E; i += stride) atomicAdd(&deg[edst[i]], 1);
        return;
    }

    const int wid = tid >> 6, L = tid & 63;
    float* xs = sX[wid];
    const float inv = 0.17677669529663687f; // 1/sqrt(32)

    const bool t0 = (L < 32);
    const int i1 = t0 ? 0 : (L - 32);
    const int v1 = i1 / 3, c1 = i1 - v1 * 3;
    const int i2 = L + 32;
    const int v2 = i2 / 3, c2 = i2 - v2 * 3;

    const int xb1 = t0 ? 0 : (32 + c1);
    const int xst1 = t0 ? 1 : 3;

    float wA[32], wB[32], wC[32], wD[32];
#pragma unroll
    for (int u = 0; u < 32; ++u) {
        wA[u] = t0 ? Wsc0[u * 32 + L] : Wsc1[u * 32 + v1];
        wB[u] = t0 ? Wl10[u * 32 + L] : Wl11[u * 32 + v1];
        wC[u] = Wsc1[u * 32 + v2];
        wD[u] = Wl11[u * 32 + v2];
    }

    const int stride = 1024 * 4;
    for (int n = blockIdx.x * 4 + wid; n < N; n += stride) {
        xs[L]      = x[(size_t)n * 128 + L];
        xs[64 + L] = x[(size_t)n * 128 + 64 + L];
        const float scale = inv * attr[n];
        float a0 = 0.f, a1 = 0.f, b0 = 0.f, b1 = 0.f;
#pragma unroll
        for (int u = 0; u < 32; ++u) {
            const float xv1 = xs[xb1 + u * xst1];
            const float xv2 = xs[32 + u * 3 + c2];
            a0 += xv1 * wA[u];
            a1 += xv1 * wB[u];
            b0 += xv2 * wC[u];
            b1 += xv2 * wD[u];
        }
        sc_out[(size_t)n * 128 + L]      = a0 * scale;
        sc_out[(size_t)n * 128 + 64 + L] = b0 * scale;
        y_out [(size_t)n * 128 + L]      = (_Float16)(a1 * scale);
        y_out [(size_t)n * 128 + 64 + L] = (_Float16)(b1 * scale);
    }
}

// ---------------------------------------------------------------------------
// CSR build: scanA -> scanC2 (inlined scanB). (r22-verified)
// ---------------------------------------------------------------------------
__global__ __launch_bounds__(256) void scanA_kernel(
    const int* __restrict__ deg, int* __restrict__ bsum, int N)
{
    __shared__ int red[256];
    const int t = threadIdx.x, b = blockIdx.x;
    const int base = b * SCAN_CH;
    int s = 0;
#pragma unroll
    for (int k = 0; k < 4; ++k) {
        const int idx = base + t + k * 256;
        if (idx < N) s += deg[idx];
    }
    red[t] = s;
    __syncthreads();
    for (int off = 128; off; off >>= 1) {
        if (t < off) red[t] += red[t + off];
        __syncthreads();
    }
    if (t == 0) bsum[b] = red[0];
}

__global__ __launch_bounds__(256) void scanC2_kernel(
    const int* __restrict__ deg, const int* __restrict__ bsum,
    int* __restrict__ row_ptr, int N, int NB)
{
    __shared__ int sb[256];
    __shared__ int ts[256];
    const int t = threadIdx.x, b = blockIdx.x;

    sb[t] = (t < NB) ? bsum[t] : 0;
    __syncthreads();
    for (int off = 1; off < 256; off <<= 1) {
        const int add = (t >= off) ? sb[t - off] : 0;
        __syncthreads();
        sb[t] += add;
        __syncthreads();
    }
    const int boffb = (b == 0) ? 0 : sb[b - 1];
    __syncthreads();

    const int base = b * SCAN_CH + t * 4;
    int d0 = 0, d1 = 0, d2 = 0, d3 = 0;
    if (base + 0 < N) d0 = deg[base + 0];
    if (base + 1 < N) d1 = deg[base + 1];
    if (base + 2 < N) d2 = deg[base + 2];
    if (base + 3 < N) d3 = deg[base + 3];
    const int tsum = d0 + d1 + d2 + d3;
    ts[t] = tsum;
    __syncthreads();
    for (int off = 1; off < 256; off <<= 1) {
        const int add = (t >= off) ? ts[t - off] : 0;
        __syncthreads();
        ts[t] += add;
        __syncthreads();
    }
    int run = boffb + ts[t] - tsum;
    if (base + 0 <= N) row_ptr[base + 0] = run;
    run += d0;
    if (base + 1 <= N) row_ptr[base + 1] = run;
    run += d1;
    if (base + 2 <= N) row_ptr[base + 2] = run;
    run += d2;
    if (base + 3 <= N) row_ptr[base + 3] = run;
}

// ---------------------------------------------------------------------------
// fill: scatter edge data into CSR order, now INCLUDING escal rows (padded
// to 12 floats) so edge_w reads everything sequentially.
// ---------------------------------------------------------------------------
__global__ void fill_kernel(
    const int* __restrict__ esrc, const int* __restrict__ edst,
    const float* __restrict__ esh, const float* __restrict__ escal,
    const int* __restrict__ row_ptr, int* __restrict__ cur,
    int* __restrict__ src_s, float4* __restrict__ sh_s,
    float* __restrict__ escal_s, int E)
{
    int i = blockIdx.x * blockDim.x + threadIdx.x;
    const int stride = gridDim.x * blockDim.x;
    for (; i < E; i += stride) {
        const int d = edst[i];
        const int p = row_ptr[d] + atomicAdd(&cur[d], 1);
        src_s[p] = esrc[i];
        sh_s[p] = *(const float4*)&esh[(size_t)i * 4];
        const float* es = escal + (size_t)i * 10;
        float* eo = escal_s + (size_t)p * 12;
        *(float4*)eo       = *(const float4*)es;
        *(float4*)(eo + 4) = *(const float4*)(es + 4);
        eo[8] = es[8];
        eo[9] = es[9];
    }
}

// ---------------------------------------------------------------------------
// Kernel B: edge MLP -> w (f16, CSR-slot order). All address streams now
// SEQUENTIAL: escal_s rows (padded 12) in, w_s rows out. Structure otherwise
// r20/r22-exact (512 thr, 8 waves share W2T, grid 512, 2-deep prefetch).
// ---------------------------------------------------------------------------
__global__ __launch_bounds__(512) void edge_w_kernel(
    const float* __restrict__ escal_s,
    const float* __restrict__ Wfc1, const float* __restrict__ Wfc2,
    _Float16* __restrict__ w_s, int E)
{
    __shared__ _Float16 sW2T[128 * 128];   // 32 KB, [col][k] swizzled
    __shared__ _Float16 sH[8][16 * 128];   // 4 KB per wave (h, then w staging)

    const int tid = threadIdx.x;
    const int wid = tid >> 6;              // wave 0..7
    const int l   = tid & 63;
    const int c16 = l & 15;
    const int kq  = l >> 4;

    _Float16* Hw = sH[wid];

    {
        int* z2 = (int*)sW2T;
        for (int i = tid; i < 128 * 128 / 2; i += 512) z2[i] = 0;
    }
    __syncthreads();
    for (int i = tid; i < 100 * 128; i += 512) {
        const int k = i >> 7, col = i & 127;
        sW2T[col * 128 + (k ^ ((col & 7) << 3))] = (_Float16)Wfc2[i];
    }

    f16x8 bW1[7];
#pragma unroll
    for (int cb = 0; cb < 7; ++cb) {
        const int col = cb * 16 + c16;
#pragma unroll
        for (int j = 0; j < 8; ++j) {
            const int k = kq * 8 + j;
            bW1[cb][j] = (k < 10 && col < 100) ? (_Float16)Wfc1[k * 100 + col]
                                               : (_Float16)0.f;
        }
    }
#pragma unroll
    for (int r = 0; r < 4; ++r) {
        const int row = kq * 4 + r;
        const int col = 112 + c16;
        Hw[row * 128 + (col ^ ((row & 7) << 3))] = (_Float16)0.f;
    }
    __syncthreads();   // W2T visible to all waves; no barriers after this

    const float inv_s10 = 0.31622776601683794f; // 1/sqrt(10)

    const int gw = blockIdx.x * 8 + wid;
    const int nw = gridDim.x * 8;
    const int step = nw * 16;

// sequential escal_s row read (pad 12)
#define LOAD_A1(DST, B)                                                       \
    {                                                                         \
        const int ge_ = (B) + c16;                                            \
        _Pragma("unroll")                                                     \
        for (int j_ = 0; j_ < 8; ++j_) {                                      \
            const int k_ = kq * 8 + j_;                                       \
            (DST)[j_] = (k_ < 10 && ge_ < E)                                  \
                        ? (_Float16)escal_s[(size_t)ge_ * 12 + k_]            \
                        : (_Float16)0.f;                                      \
        }                                                                     \
    }

    int base = gw * 16;
    f16x8 a1;
    LOAD_A1(a1, base)

    for (; base < E; base += step) {
#pragma unroll
        for (int cb = 0; cb < 7; ++cb) {
            f32x4 z = {0.f, 0.f, 0.f, 0.f};
            z = __builtin_amdgcn_mfma_f32_16x16x32_f16(a1, bW1[cb], z, 0, 0, 0);
#pragma unroll
            for (int r = 0; r < 4; ++r) {
                const int row = kq * 4 + r;
                const int col = cb * 16 + c16;
                const float h = silu_f(z[r] * inv_s10) * 0.1f;
                Hw[row * 128 + (col ^ ((row & 7) << 3))] = (_Float16)h;
            }
        }

        f16x8 a1n;
        LOAD_A1(a1n, base + step)

        f32x4 acc0 = {0.f,0.f,0.f,0.f}, acc1 = {0.f,0.f,0.f,0.f};
        f32x4 acc2 = {0.f,0.f,0.f,0.f}, acc3 = {0.f,0.f,0.f,0.f};
        f32x4 acc4 = {0.f,0.f,0.f,0.f}, acc5 = {0.f,0.f,0.f,0.f};
        f32x4 acc6 = {0.f,0.f,0.f,0.f}, acc7 = {0.f,0.f,0.f,0.f};
#pragma unroll
        for (int kk = 0; kk < 4; ++kk) {
            const f16x8 a2 = *(const f16x8*)&Hw[c16 * 128 +
                                ((kk * 32 + kq * 8) ^ ((c16 & 7) << 3))];
#define BFRAG(CB) (*(const f16x8*)&sW2T[((CB) * 16 + c16) * 128 + \
                       ((kk * 32 + kq * 8) ^ ((c16 & 7) << 3))])
            acc0 = __builtin_amdgcn_mfma_f32_16x16x32_f16(a2, BFRAG(0), acc0, 0, 0, 0);
            acc1 = __builtin_amdgcn_mfma_f32_16x16x32_f16(a2, BFRAG(1), acc1, 0, 0, 0);
            acc2 = __builtin_amdgcn_mfma_f32_16x16x32_f16(a2, BFRAG(2), acc2, 0, 0, 0);
            acc3 = __builtin_amdgcn_mfma_f32_16x16x32_f16(a2, BFRAG(3), acc3, 0, 0, 0);
            acc4 = __builtin_amdgcn_mfma_f32_16x16x32_f16(a2, BFRAG(4), acc4, 0, 0, 0);
            acc5 = __builtin_amdgcn_mfma_f32_16x16x32_f16(a2, BFRAG(5), acc5, 0, 0, 0);
            acc6 = __builtin_amdgcn_mfma_f32_16x16x32_f16(a2, BFRAG(6), acc6, 0, 0, 0);
            acc7 = __builtin_amdgcn_mfma_f32_16x16x32_f16(a2, BFRAG(7), acc7, 0, 0, 0);
#undef BFRAG
        }

#define STAGE_CB(CB, ACC)                                                     \
        {                                                                     \
            _Pragma("unroll")                                                 \
            for (int r = 0; r < 4; ++r) {                                     \
                const int row = kq * 4 + r;                                   \
                const int col = (CB) * 16 + c16;                              \
                Hw[row * 128 + (col ^ ((row & 7) << 3))] = (_Float16)(ACC)[r];\
            }                                                                 \
        }
        STAGE_CB(0, acc0) STAGE_CB(1, acc1) STAGE_CB(2, acc2) STAGE_CB(3, acc3)
        STAGE_CB(4, acc4) STAGE_CB(5, acc5) STAGE_CB(6, acc6) STAGE_CB(7, acc7)
#undef STAGE_CB

#pragma unroll
        for (int i = 0; i < 4; ++i) {
            const int e = i * 4 + (l >> 4);
            const int colb = (l & 15) * 8;
            const f16x8 v = *(const f16x8*)&Hw[e * 128 +
                                (colb ^ ((e & 7) << 3))];
            if (base + e < E)
                *(f16x8*)&w_s[(size_t)(base + e) * 128 + colb] = v;
        }

        a1 = a1n;
    }
#undef LOAD_A1
}

// ---------------------------------------------------------------------------
// Kernel C: gather + mean + fused post. (r20/r22-verified)
// ---------------------------------------------------------------------------
__global__ __launch_bounds__(256) void gather_post_kernel(
    const _Float16* __restrict__ w_s, const int* __restrict__ src_s,
    const float4* __restrict__ sh_s, const int* __restrict__ row_ptr,
    const _Float16* __restrict__ y, const float* __restrict__ attr,
    const float* __restrict__ Wl20, const float* __restrict__ Wl21,
    const float* __restrict__ Walpha,
    float* __restrict__ out, int N)
{
    __shared__ float sW0T[32 * 68];   // [o][u] padded
    __shared__ float sW1T[32 * 68];   // [o][u] padded
    __shared__ float sWa[64];
    __shared__ float sMid[4][256];    // per-wave: [mid0(64) | midT(3x64)]

    const int tid = threadIdx.x;
    for (int i = tid; i < 64 * 32; i += 256) {
        const int u = i >> 5, o = i & 31;
        sW0T[o * 68 + u] = Wl20[i];
        sW1T[o * 68 + u] = Wl21[i];
    }
    if (tid < 64) sWa[tid] = Walpha[tid];
    __syncthreads();   // only barrier; node loop is barrier-free

    const int wid = tid >> 6;
    const int L   = tid & 63;
    const bool hi = (L >= 32);
    const int u   = L & 31;

    const int wAi = hi ? 32 + u : u;
    const int wBi = hi ? 96 + u : 64 + u;
    const int yi0 = hi ? 32 + 3 * u + 0 : u;
    const int yi1 = hi ? 32 + 3 * u + 1 : u;
    const int yi2 = hi ? 32 + 3 * u + 2 : u;
    const float mulA = hi ? 0.5773502691896258f : 1.0f;   // 1/sqrt(3) on m11

    const int o1m = L - 32;
    const int v1 = hi ? o1m / 3 : 0;
    const int c1 = hi ? o1m - v1 * 3 : 0;
    const int o2m = L + 32;
    const int v2 = o2m / 3;
    const int c2 = o2m - v2 * 3;
    const float* wrow1 = hi ? (sW1T + v1 * 68) : (sW0T + L * 68);
    const float* wrow2 = sW1T + v2 * 68;

    float* midw = &sMid[wid][0];
    const float* msrc1c = hi ? (midw + 64 + c1 * 64) : midw;
    const float* msrc2c = midw + 64 + c2 * 64;

#define ACC_EDGE(sh, wAv, wBv, q0, q1, q2) do {                        \
        const float sA0 = hi ? (sh).y : (sh).x;                        \
        const float sA1 = hi ? (sh).z : 0.f;                           \
        const float sA2 = hi ? (sh).w : 0.f;                           \
        const float b1s = hi ? (sh).x : (sh).y;                        \
        const float b2s = hi ? (sh).x : (sh).z;                        \
        const float b3s = hi ? (sh).x : (sh).w;                        \
        accA += (wAv) * mulA * ((q0) * sA0 + (q1) * sA1 + (q2) * sA2); \
        acc1 += (wBv) * (q0) * b1s;                                    \
        acc2 += (wBv) * (q1) * b2s;                                    \
        acc3 += (wBv) * (q2) * b3s;                                    \
    } while (0)

    const int waves_glob = gridDim.x * 4;
    for (int n = blockIdx.x * 4 + wid; n < N; n += waves_glob) {
        const int jlo = row_ptr[n];
        const int jhi = row_ptr[n + 1];
        const int deg = jhi - jlo;
        if (deg <= 0) continue;

        float accA = 0.f, acc1 = 0.f, acc2 = 0.f, acc3 = 0.f;

        int j = jlo;
        for (; j + 2 <= jhi; j += 2) {
            const int sa = src_s[j];
            const int sb = src_s[j + 1];
            const float4 shA = sh_s[j];
            const float4 shB = sh_s[j + 1];
            const _Float16* wra = w_s + (size_t)j * 128;
            const _Float16* wrb = wra + 128;
            const _Float16* yra = y + (size_t)sa * 128;
            const _Float16* yrb = y + (size_t)sb * 128;
            const float wAa = (float)wra[wAi], wBa = (float)wra[wBi];
            const float qa0 = (float)yra[yi0], qa1 = (float)yra[yi1], qa2 = (float)yra[yi2];
            const float wAb = (float)wrb[wAi], wBb = (float)wrb[wBi];
            const float qb0 = (float)yrb[yi0], qb1 = (float)yrb[yi1], qb2 = (float)yrb[yi2];
            ACC_EDGE(shA, wAa, wBa, qa0, qa1, qa2);
            ACC_EDGE(shB, wAb, wBb, qb0, qb1, qb2);
        }
        if (j < jhi) {
            const int sa = src_s[j];
            const float4 shA = sh_s[j];
            const _Float16* wra = w_s + (size_t)j * 128;
            const _Float16* yra = y + (size_t)sa * 128;
            const float wAa = (float)wra[wAi], wBa = (float)wra[wBi];
            const float qa0 = (float)yra[yi0], qa1 = (float)yra[yi1], qa2 = (float)yra[yi2];
            ACC_EDGE(shA, wAa, wBa, qa0, qa1, qa2);
        }

        const float rdeg = 1.0f / (float)deg;
        const float a = attr[n];

        float term = accA * rdeg * sWa[L];
#pragma unroll
        for (int off = 32; off; off >>= 1) term += __shfl_xor(term, off);
        const float alpha = term * 0.125f * a;

        midw[L]            = accA * rdeg;
        midw[64 + L]       = acc1 * rdeg;
        midw[128 + L]      = acc2 * rdeg;
        midw[192 + L]      = acc3 * rdeg;

        float cv1 = 0.f, cv2 = 0.f;
#pragma unroll
        for (int kk = 0; kk < 16; ++kk) {
            const float4 m1 = *(const float4*)&msrc1c[4 * kk];
            const float4 m2 = *(const float4*)&msrc2c[4 * kk];
            const float4 w1 = *(const float4*)&wrow1[4 * kk];
            const float4 w2 = *(const float4*)&wrow2[4 * kk];
            cv1 += m1.x * w1.x + m1.y * w1.y + m1.z * w1.z + m1.w * w1.w;
            cv2 += m2.x * w2.x + m2.y * w2.y + m2.z * w2.z + m2.w * w2.w;
        }
        const float f = alpha * 0.125f * a;
        const size_t ob = (size_t)n * 128;
        out[ob + L]      += f * cv1;
        out[ob + 64 + L] += f * cv2;
    }
#undef ACC_EDGE
}

extern "C" void kernel_launch(void* const* d_in, const int* in_sizes, int n_in,
                              void* d_out, int out_size, void* d_ws, size_t ws_size,
                              hipStream_t stream)
{
    const float* x      = (const float*)d_in[0];
    const float* attr   = (const float*)d_in[1];
    const int*   esrc   = (const int*)  d_in[2];
    const int*   edst   = (const int*)  d_in[3];
    const float* esh    = (const float*)d_in[4];
    const float* escal  = (const float*)d_in[5];
    const float* Wfc1   = (const float*)d_in[6];
    const float* Wfc2   = (const float*)d_in[7];
    const float* Wsc0   = (const float*)d_in[8];
    const float* Wsc1   = (const float*)d_in[9];
    const float* Wl10   = (const float*)d_in[10];
    const float* Wl11   = (const float*)d_in[11];
    const float* Wl20   = (const float*)d_in[12];
    const float* Wl21   = (const float*)d_in[13];
    const float* Walpha = (const float*)d_in[14];

    const int N = in_sizes[1];
    const int E = in_sizes[2];
    float* out = (float*)d_out;

    // ws: y(f16) | row_ptr | deg | cur | bsum | src_s | [align16] sh_s |
    //     escal_s(E*12 f32) | w_s
    char* p = (char*)d_ws;
    _Float16* y   = (_Float16*)p; p += (size_t)N * 128 * sizeof(_Float16);
    int* row_ptr  = (int*)p;      p += (size_t)(N + 1) * sizeof(int);
    int* deg      = (int*)p;      p += (size_t)N * sizeof(int);
    int* cur      = (int*)p;      p += (size_t)N * sizeof(int);
    int* bsum     = (int*)p;      p += 256 * sizeof(int);
    int* src_s    = (int*)p;      p += (size_t)E * sizeof(int);
    p = (char*)(((uintptr_t)p + 15) & ~(uintptr_t)15);
    float4* sh_s  = (float4*)p;   p += (size_t)E * sizeof(float4);
    float* escal_s = (float*)p;   p += (size_t)E * 12 * sizeof(float);
    _Float16* w_s = (_Float16*)p;

    const int NB = (N + SCAN_CH) / SCAN_CH;   // covers row_ptr[N]

    hipMemsetAsync(deg, 0, (size_t)2 * N * sizeof(int), stream);

    pre_hist_kernel<<<1536, 256, 0, stream>>>(x, attr, Wsc0, Wsc1, Wl10, Wl11,
                                              out, y, N, edst, deg, E);
    scanA_kernel<<<NB, 256, 0, stream>>>(deg, bsum, N);
    scanC2_kernel<<<NB, 256, 0, stream>>>(deg, bsum, row_ptr, N, NB);
    fill_kernel<<<512, 256, 0, stream>>>(esrc, edst, esh, escal, row_ptr, cur,
                                         src_s, sh_s, escal_s, E);
    edge_w_kernel<<<512, 512, 0, stream>>>(escal_s, Wfc1, Wfc2, w_s, E);
    gather_post_kernel<<<4096, 256, 0, stream>>>(w_s, src_s, sh_s, row_ptr,
                                                 y, attr, Wl20, Wl21, Walpha,
                                                 out, N);
}